// Round 1
// baseline (968.699 us; speedup 1.0000x reference)
//
#include <hip/hip_runtime.h>
#include <math.h>

// Problem constants
#define BB 4
#define SS 1024
#define DD 1024
#define HH 16
#define DHH 64
#define NROWS (BB * SS)   // 4096

// ---------------------------------------------------------------------------
// Generic C = A@B + bias GEMM. A[M,K] row-major, B[K,N] row-major, C[M,N].
// 64x64 tile, BK=16, 256 threads, 4x4 micro-tile per thread.
// M,N,K assumed multiples of 64/64/16 (true for all 3 calls here).
// ---------------------------------------------------------------------------
__global__ __launch_bounds__(256) void gemm_bias_kernel(
    const float* __restrict__ A, const float* __restrict__ B,
    const float* __restrict__ bias, float* __restrict__ C,
    int M, int N, int K)
{
    __shared__ float As[16][65];  // [k][m] transposed, +1 pad
    __shared__ float Bs[16][68];  // [k][n], +4 pad (keeps float4 stores aligned)

    const int t  = threadIdx.x;
    const int tx = t & 15;        // 0..15 -> n micro
    const int ty = t >> 4;        // 0..15 -> m micro
    const int bm = blockIdx.y * 64;
    const int bn = blockIdx.x * 64;

    // A-tile load: 64 rows x 16 cols, one float4 per thread
    const int arow = t >> 2;          // 0..63
    const int acol = (t & 3) * 4;     // 0,4,8,12
    // B-tile load: 16 rows x 64 cols, one float4 per thread
    const int brow = t >> 4;          // 0..15
    const int bcol = (t & 15) * 4;    // 0..60

    const float* Aptr = A + (bm + arow) * K + acol;
    const float* Bptr = B + brow * N + bn + bcol;

    float acc[4][4] = {};

    for (int k0 = 0; k0 < K; k0 += 16) {
        float4 av = *(const float4*)(Aptr + k0);
        float4 bv = *(const float4*)(Bptr + k0 * N);
        As[acol + 0][arow] = av.x;
        As[acol + 1][arow] = av.y;
        As[acol + 2][arow] = av.z;
        As[acol + 3][arow] = av.w;
        *(float4*)&Bs[brow][bcol] = bv;
        __syncthreads();

        #pragma unroll
        for (int kk = 0; kk < 16; ++kk) {
            float a[4], b[4];
            #pragma unroll
            for (int i = 0; i < 4; ++i) a[i] = As[kk][ty * 4 + i];
            #pragma unroll
            for (int j = 0; j < 4; ++j) b[j] = Bs[kk][tx * 4 + j];
            #pragma unroll
            for (int i = 0; i < 4; ++i)
                #pragma unroll
                for (int j = 0; j < 4; ++j)
                    acc[i][j] += a[i] * b[j];
        }
        __syncthreads();
    }

    // Epilogue: add bias, store float4 rows
    float4 bia = *(const float4*)&bias[bn + tx * 4];
    #pragma unroll
    for (int i = 0; i < 4; ++i) {
        float4 o;
        o.x = acc[i][0] + bia.x;
        o.y = acc[i][1] + bia.y;
        o.z = acc[i][2] + bia.z;
        o.w = acc[i][3] + bia.w;
        *(float4*)&C[(bm + ty * 4 + i) * N + bn + tx * 4] = o;
    }
}

// ---------------------------------------------------------------------------
// Flash-style causal attention over the fused QKV buffer.
// qkv layout: [B*S, 3*D]; head h occupies cols h*64..h*64+63 of each third.
// Output aout: [B, S, H*DH] = [B*S, 1024] (merge-heads layout).
// Grid: (S/64, B*H). Block: 256 threads (16x16), 4x4 micro-tile.
// ---------------------------------------------------------------------------
__global__ __launch_bounds__(256) void attn_kernel(
    const float* __restrict__ qkv, float* __restrict__ aout)
{
    __shared__ float Qs[64][68];   // [qrow][d]
    __shared__ float KsT[64][68];  // [d][key]  (transposed on store)
    __shared__ float Vs[64][68];   // [key][d]
    __shared__ float Ps[64][68];   // [qrow][key]

    const int t  = threadIdx.x;
    const int tx = t & 15;
    const int ty = t >> 4;
    const int qb = blockIdx.x;          // q tile, 0..15
    const int bh = blockIdx.y;          // 0..63
    const int b  = bh >> 4;
    const int h  = bh & 15;

    const int base = (b * SS) * (3 * DD) + h * DHH;  // fits in int (max ~37M)

    // Load Q tile: 64 rows x 64 cols; 4 float4 per thread
    const int lr = t >> 4;          // 0..15
    const int lc = (t & 15) * 4;    // 0..60
    #pragma unroll
    for (int i = 0; i < 4; ++i) {
        int r = lr + i * 16;
        float4 v = *(const float4*)&qkv[base + (qb * 64 + r) * (3 * DD) + lc];
        *(float4*)&Qs[r][lc] = v;
    }

    float m[4], l[4], o[4][4];
    #pragma unroll
    for (int i = 0; i < 4; ++i) {
        m[i] = -INFINITY;
        l[i] = 0.0f;
        #pragma unroll
        for (int j = 0; j < 4; ++j) o[i][j] = 0.0f;
    }
    const float scale = 0.125f;  // 1/sqrt(64)

    for (int kb = 0; kb <= qb; ++kb) {
        __syncthreads();  // previous PV done (and Q visible on first iter)
        // Load K tile (transposed into KsT) and V tile
        #pragma unroll
        for (int i = 0; i < 4; ++i) {
            int r = lr + i * 16;
            float4 kv = *(const float4*)&qkv[base + DD + (kb * 64 + r) * (3 * DD) + lc];
            KsT[lc + 0][r] = kv.x;
            KsT[lc + 1][r] = kv.y;
            KsT[lc + 2][r] = kv.z;
            KsT[lc + 3][r] = kv.w;
            float4 vv = *(const float4*)&qkv[base + 2 * DD + (kb * 64 + r) * (3 * DD) + lc];
            *(float4*)&Vs[r][lc] = vv;
        }
        __syncthreads();

        // S = Q K^T  (4x4 micro-tile per thread)
        float s[4][4] = {};
        #pragma unroll
        for (int k = 0; k < 64; ++k) {
            float a[4], kvv[4];
            #pragma unroll
            for (int i = 0; i < 4; ++i) a[i] = Qs[ty * 4 + i][k];
            #pragma unroll
            for (int j = 0; j < 4; ++j) kvv[j] = KsT[k][tx * 4 + j];
            #pragma unroll
            for (int i = 0; i < 4; ++i)
                #pragma unroll
                for (int j = 0; j < 4; ++j)
                    s[i][j] += a[i] * kvv[j];
        }

        // scale + causal mask (diagonal tile only)
        #pragma unroll
        for (int i = 0; i < 4; ++i)
            #pragma unroll
            for (int j = 0; j < 4; ++j) {
                s[i][j] *= scale;
                if (kb == qb && (tx * 4 + j) > (ty * 4 + i)) s[i][j] = -INFINITY;
            }

        // Row max across the tile (reduce over tx: lane bits 0..3)
        float rmax[4];
        #pragma unroll
        for (int i = 0; i < 4; ++i)
            rmax[i] = fmaxf(fmaxf(s[i][0], s[i][1]), fmaxf(s[i][2], s[i][3]));
        #pragma unroll
        for (int off = 1; off < 16; off <<= 1)
            #pragma unroll
            for (int i = 0; i < 4; ++i)
                rmax[i] = fmaxf(rmax[i], __shfl_xor(rmax[i], off));

        float mn[4], al[4], rsum[4];
        float p[4][4];
        #pragma unroll
        for (int i = 0; i < 4; ++i) {
            mn[i] = fmaxf(m[i], rmax[i]);
            al[i] = expf(m[i] - mn[i]);   // exp(-inf)=0 on first tile
            rsum[i] = 0.0f;
            #pragma unroll
            for (int j = 0; j < 4; ++j) {
                p[i][j] = expf(s[i][j] - mn[i]);
                rsum[i] += p[i][j];
            }
        }
        #pragma unroll
        for (int off = 1; off < 16; off <<= 1)
            #pragma unroll
            for (int i = 0; i < 4; ++i)
                rsum[i] += __shfl_xor(rsum[i], off);

        #pragma unroll
        for (int i = 0; i < 4; ++i) {
            l[i] = l[i] * al[i] + rsum[i];
            m[i] = mn[i];
            #pragma unroll
            for (int j = 0; j < 4; ++j) o[i][j] *= al[i];
            float4 pv = make_float4(p[i][0], p[i][1], p[i][2], p[i][3]);
            *(float4*)&Ps[ty * 4 + i][tx * 4] = pv;
        }
        __syncthreads();

        // O += P @ V
        #pragma unroll
        for (int k = 0; k < 64; ++k) {
            float pa[4], vv[4];
            #pragma unroll
            for (int i = 0; i < 4; ++i) pa[i] = Ps[ty * 4 + i][k];
            #pragma unroll
            for (int j = 0; j < 4; ++j) vv[j] = Vs[k][tx * 4 + j];
            #pragma unroll
            for (int i = 0; i < 4; ++i)
                #pragma unroll
                for (int j = 0; j < 4; ++j)
                    o[i][j] += pa[i] * vv[j];
        }
    }

    // Epilogue: normalize by l, write merge-heads layout [B*S, 1024]
    #pragma unroll
    for (int i = 0; i < 4; ++i) {
        float inv = 1.0f / l[i];
        float4 ov;
        ov.x = o[i][0] * inv;
        ov.y = o[i][1] * inv;
        ov.z = o[i][2] * inv;
        ov.w = o[i][3] * inv;
        int row = b * SS + qb * 64 + ty * 4 + i;
        *(float4*)&aout[row * DD + h * DHH + tx * 4] = ov;
    }
}

extern "C" void kernel_launch(void* const* d_in, const int* in_sizes, int n_in,
                              void* d_out, int out_size, void* d_ws, size_t ws_size,
                              hipStream_t stream)
{
    const float* x     = (const float*)d_in[0];  // [4,1024,1024]
    const float* wqkv  = (const float*)d_in[1];  // [1024,3072]
    const float* bqkv  = (const float*)d_in[2];  // [3072]
    const float* wproj = (const float*)d_in[3];  // [1024,1024]
    const float* bproj = (const float*)d_in[4];  // [1024]
    float* out = (float*)d_out;                  // [4,1024,1024]

    float* qkv  = (float*)d_ws;                        // 4096*3072 floats = 50.3 MB
    float* abuf = qkv + (size_t)NROWS * (3 * DD);      // 4096*1024 floats = 16.8 MB

    dim3 blk(256);

    // 1) QKV projection: [4096,1024]@[1024,3072]+b
    gemm_bias_kernel<<<dim3(3 * DD / 64, NROWS / 64), blk, 0, stream>>>(
        x, wqkv, bqkv, qkv, NROWS, 3 * DD, DD);

    // 2) Causal flash attention per (b,h,q-tile)
    attn_kernel<<<dim3(SS / 64, BB * HH), blk, 0, stream>>>(qkv, abuf);

    // 3) Output projection: [4096,1024]@[1024,1024]+b
    gemm_bias_kernel<<<dim3(DD / 64, NROWS / 64), blk, 0, stream>>>(
        abuf, wproj, bproj, out, NROWS, DD, DD);
}

// Round 2
// 240.759 us; speedup vs baseline: 4.0235x; 4.0235x over previous
//
#include <hip/hip_runtime.h>
#include <math.h>

#define BB 4
#define SS 1024
#define DD 1024
#define HH 16
#define DHH 64
#define NROWS (BB * SS)   // 4096

typedef short bf16x8 __attribute__((ext_vector_type(8)));
typedef float f32x4 __attribute__((ext_vector_type(4)));

// fp32 -> bf16 round-to-nearest-even
__device__ __forceinline__ unsigned short f2bf(float f) {
    unsigned u = __float_as_uint(f);
    u += 0x7fffu + ((u >> 16) & 1u);
    return (unsigned short)(u >> 16);
}

// async global->LDS, 16B per lane; LDS dest = wave-uniform base + lane*16
__device__ __forceinline__ void glds16(const void* g, void* l) {
    __builtin_amdgcn_global_load_lds(
        (const __attribute__((address_space(1))) unsigned int*)g,
        (__attribute__((address_space(3))) unsigned int*)l, 16, 0, 0);
}

// 32B-granule XOR swizzle within a 64-col (128B) logical row.
// Breaks the 8-way bank conflict of strided MFMA fragment reads at
// row-stride 160B while keeping 16B alignment of b128 accesses.
__device__ __forceinline__ int swz(int row, int col) {
    return ((((col >> 4) ^ (row >> 2)) & 3) << 4) | (col & 15);
}

// ---------------------------------------------------------------------------
// fp32 -> bf16 bulk cast (n4 = element count / 4)
// ---------------------------------------------------------------------------
__global__ __launch_bounds__(256) void cast_bf16_kernel(
    const float* __restrict__ in, unsigned short* __restrict__ out, int n4)
{
    int i = blockIdx.x * 256 + threadIdx.x;
    if (i < n4) {
        float4 v = ((const float4*)in)[i];
        ushort4 o = { f2bf(v.x), f2bf(v.y), f2bf(v.z), f2bf(v.w) };
        ((ushort4*)out)[i] = o;
    }
}

// ---------------------------------------------------------------------------
// W[K][N] fp32 -> Wt[N][K] bf16 (tiled transpose, 64x64 per block)
// ---------------------------------------------------------------------------
__global__ __launch_bounds__(256) void tcast_kernel(
    const float* __restrict__ W, unsigned short* __restrict__ Wt, int K, int N)
{
    __shared__ float tile[64][65];
    int n0 = blockIdx.x * 64, k0 = blockIdx.y * 64;
    int c = threadIdx.x & 63, r0 = threadIdx.x >> 6;
    #pragma unroll
    for (int i = 0; i < 16; ++i) {
        int r = r0 + i * 4;
        tile[r][c] = W[(size_t)(k0 + r) * N + n0 + c];
    }
    __syncthreads();
    #pragma unroll
    for (int i = 0; i < 16; ++i) {
        int r = r0 + i * 4;  // n-local
        Wt[(size_t)(n0 + r) * K + k0 + c] = f2bf(tile[c][r]);
    }
}

// ---------------------------------------------------------------------------
// Extract+transpose V third of qkv: Vt[bh][dh=64][S=1024] bf16
// ---------------------------------------------------------------------------
__global__ __launch_bounds__(256) void vtrans_kernel(
    const unsigned short* __restrict__ qkv, unsigned short* __restrict__ Vt)
{
    __shared__ unsigned short tile[64][65];
    int kb = blockIdx.x;           // S tile
    int bh = blockIdx.y;           // b*16+h
    int b = bh >> 4, h = bh & 15;
    int c = threadIdx.x & 63, r0 = threadIdx.x >> 6;
    size_t base = (size_t)b * SS * 3072 + 2048 + h * 64;
    #pragma unroll
    for (int i = 0; i < 16; ++i) {
        int r = r0 + i * 4;  // key row
        tile[r][c] = qkv[base + (size_t)(kb * 64 + r) * 3072 + c];
    }
    __syncthreads();
    #pragma unroll
    for (int i = 0; i < 16; ++i) {
        int d = r0 + i * 4;  // dh row
        Vt[((size_t)bh * 64 + d) * 1024 + kb * 64 + c] = tile[c][d];
    }
}

// ---------------------------------------------------------------------------
// MFMA bf16 GEMM: C = A[M,K] @ B + bias, with B given pre-transposed
// Bt[N][K]. 128x128 tile, BK=64, 4 waves (2x2 of 64x64), 16x16x32 MFMA.
// m97-style global_load_lds staging. OUT_BF16 selects epilogue dtype.
// ---------------------------------------------------------------------------
template <bool OUT_BF16>
__global__ __launch_bounds__(256) void gemm_mfma(
    const unsigned short* __restrict__ A,
    const unsigned short* __restrict__ Bt,
    const float* __restrict__ bias,
    void* __restrict__ Cout, int N, int K)
{
    __shared__ unsigned short As[128][64];
    __shared__ unsigned short Bs[128][64];

    const int t = threadIdx.x;
    const int lane = t & 63;
    const int w = t >> 6;                 // wave 0..3
    const int wm = (w >> 1) * 64;
    const int wn = (w & 1) * 64;
    const int l15 = lane & 15, quad = lane >> 4;
    const int bm = blockIdx.y * 128, bn = blockIdx.x * 128;

    const int srow = lane >> 3;           // 0..7 (row in 8-row chunk)
    const int scol = (lane & 7) * 8;      // 0..56 (bf16 col)

    const f32x4 zero4 = {0.f, 0.f, 0.f, 0.f};
    f32x4 acc[4][4];
    #pragma unroll
    for (int i = 0; i < 4; ++i)
        #pragma unroll
        for (int j = 0; j < 4; ++j) acc[i][j] = zero4;

    const unsigned short* Abase = A  + (size_t)(bm + w * 32 + srow) * K + scol;
    const unsigned short* Bbase = Bt + (size_t)(bn + w * 32 + srow) * K + scol;

    for (int k0 = 0; k0 < K; k0 += 64) {
        #pragma unroll
        for (int c = 0; c < 4; ++c) {
            glds16(Abase + (size_t)(c * 8) * K + k0, &As[w * 32 + c * 8][0]);
            glds16(Bbase + (size_t)(c * 8) * K + k0, &Bs[w * 32 + c * 8][0]);
        }
        __syncthreads();
        #pragma unroll
        for (int kk = 0; kk < 2; ++kk) {
            bf16x8 af[4], bfr[4];
            #pragma unroll
            for (int mi = 0; mi < 4; ++mi)
                af[mi] = *(const bf16x8*)&As[wm + mi * 16 + l15][kk * 32 + quad * 8];
            #pragma unroll
            for (int nj = 0; nj < 4; ++nj)
                bfr[nj] = *(const bf16x8*)&Bs[wn + nj * 16 + l15][kk * 32 + quad * 8];
            #pragma unroll
            for (int mi = 0; mi < 4; ++mi)
                #pragma unroll
                for (int nj = 0; nj < 4; ++nj)
                    acc[mi][nj] = __builtin_amdgcn_mfma_f32_16x16x32_bf16(
                        af[mi], bfr[nj], acc[mi][nj], 0, 0, 0);
        }
        __syncthreads();
    }

    // Epilogue. C/D layout: col = lane&15, row = quad*4 + reg (m89-verified).
    #pragma unroll
    for (int mi = 0; mi < 4; ++mi) {
        #pragma unroll
        for (int nj = 0; nj < 4; ++nj) {
            int col = bn + wn + nj * 16 + l15;
            float bv = bias[col];
            int row0 = bm + wm + mi * 16 + quad * 4;
            #pragma unroll
            for (int r = 0; r < 4; ++r) {
                float v = acc[mi][nj][r] + bv;
                if (OUT_BF16)
                    ((unsigned short*)Cout)[(size_t)(row0 + r) * N + col] = f2bf(v);
                else
                    ((float*)Cout)[(size_t)(row0 + r) * N + col] = v;
            }
        }
    }
}

// ---------------------------------------------------------------------------
// Flash attention, bf16 MFMA. Block = 64 q-rows of one (b,h); 4 waves,
// each wave owns 16 q-rows. Per k-tile (64 keys): QK^T (MFMA) -> online
// softmax (C-layout, shfl over lane bits 0..3) -> P via LDS round trip
// (C-layout -> A-layout, m120 pattern) -> PV (MFMA).
// ---------------------------------------------------------------------------
__global__ __launch_bounds__(256) void attn_mfma(
    const unsigned short* __restrict__ qkv,  // [B*S][3072] bf16
    const unsigned short* __restrict__ Vt,   // [64][64][1024] bf16
    unsigned short* __restrict__ aout)       // [B*S][1024] bf16
{
    __shared__ unsigned short Qs[64][80];    // plain (read once)
    __shared__ unsigned short Ks[64][80];    // swizzled
    __shared__ unsigned short VsT[64][80];   // swizzled, [dh][key]
    __shared__ unsigned short Ps[64][80];    // swizzled

    const int t = threadIdx.x;
    const int lane = t & 63;
    const int w = t >> 6;
    const int l15 = lane & 15, quad = lane >> 4;
    const int qb = blockIdx.x, bh = blockIdx.y;
    const int b = bh >> 4, h = bh & 15;
    const size_t qkvbase = (size_t)b * SS * 3072;
    const f32x4 zero4 = {0.f, 0.f, 0.f, 0.f};

    // stage Q tile (64x64)
    {
        int g = t;
        #pragma unroll
        for (int it = 0; it < 2; ++it, g += 256) {
            int r = g >> 3, cc = (g & 7) * 8;
            bf16x8 v = *(const bf16x8*)&qkv[qkvbase + (size_t)(qb * 64 + r) * 3072 + h * 64 + cc];
            *(bf16x8*)&Qs[r][cc] = v;
        }
    }
    __syncthreads();
    bf16x8 qf[2];
    qf[0] = *(const bf16x8*)&Qs[w * 16 + l15][quad * 8];
    qf[1] = *(const bf16x8*)&Qs[w * 16 + l15][32 + quad * 8];

    float mrow[4], lrow[4];
    f32x4 o[4];
    #pragma unroll
    for (int r = 0; r < 4; ++r) { mrow[r] = -INFINITY; lrow[r] = 0.f; }
    #pragma unroll
    for (int nj = 0; nj < 4; ++nj) o[nj] = zero4;
    const float scale = 0.125f;  // 1/sqrt(64)

    for (int kb = 0; kb <= qb; ++kb) {
        __syncthreads();  // all waves done reading Ks/VsT of previous tile
        {
            int g = t;
            #pragma unroll
            for (int it = 0; it < 2; ++it, g += 256) {
                int r = g >> 3, cc = (g & 7) * 8;
                bf16x8 kv = *(const bf16x8*)&qkv[qkvbase + (size_t)(kb * 64 + r) * 3072 + 1024 + h * 64 + cc];
                *(bf16x8*)&Ks[r][swz(r, cc)] = kv;
                bf16x8 vv = *(const bf16x8*)&Vt[((size_t)bh * 64 + r) * 1024 + kb * 64 + cc];
                *(bf16x8*)&VsT[r][swz(r, cc)] = vv;
            }
        }
        __syncthreads();

        // S = Q K^T : rows q (C rows), cols key (C cols)
        f32x4 s[4];
        #pragma unroll
        for (int nj = 0; nj < 4; ++nj) {
            int n = nj * 16 + l15;
            f32x4 sa = zero4;
            bf16x8 b0 = *(const bf16x8*)&Ks[n][swz(n, quad * 8)];
            bf16x8 b1 = *(const bf16x8*)&Ks[n][swz(n, 32 + quad * 8)];
            sa = __builtin_amdgcn_mfma_f32_16x16x32_bf16(qf[0], b0, sa, 0, 0, 0);
            sa = __builtin_amdgcn_mfma_f32_16x16x32_bf16(qf[1], b1, sa, 0, 0, 0);
            s[nj] = sa;
        }

        // scale + causal mask (diagonal tile only)
        #pragma unroll
        for (int nj = 0; nj < 4; ++nj) {
            #pragma unroll
            for (int r = 0; r < 4; ++r) {
                float sv = s[nj][r] * scale;
                if (kb == qb) {
                    int keyloc = nj * 16 + l15;
                    int qloc = w * 16 + quad * 4 + r;
                    if (keyloc > qloc) sv = -INFINITY;
                }
                s[nj][r] = sv;
            }
        }

        // online softmax: row lives across the 16 lanes of a quad (bits 0..3)
        float rmax[4];
        #pragma unroll
        for (int r = 0; r < 4; ++r)
            rmax[r] = fmaxf(fmaxf(s[0][r], s[1][r]), fmaxf(s[2][r], s[3][r]));
        #pragma unroll
        for (int off = 1; off < 16; off <<= 1)
            #pragma unroll
            for (int r = 0; r < 4; ++r)
                rmax[r] = fmaxf(rmax[r], __shfl_xor(rmax[r], off));

        float p[4][4], rs[4];
        #pragma unroll
        for (int r = 0; r < 4; ++r) {
            float mn = fmaxf(mrow[r], rmax[r]);
            float al = __expf(mrow[r] - mn);  // exp(-inf)=0 on first tile
            mrow[r] = mn;
            rs[r] = 0.f;
            #pragma unroll
            for (int nj = 0; nj < 4; ++nj) {
                p[nj][r] = __expf(s[nj][r] - mn);
                rs[r] += p[nj][r];
            }
            lrow[r] *= al;
            #pragma unroll
            for (int nj = 0; nj < 4; ++nj) o[nj][r] *= al;
        }
        #pragma unroll
        for (int off = 1; off < 16; off <<= 1)
            #pragma unroll
            for (int r = 0; r < 4; ++r)
                rs[r] += __shfl_xor(rs[r], off);
        #pragma unroll
        for (int r = 0; r < 4; ++r) lrow[r] += rs[r];

        // P: C-layout regs -> LDS (each wave writes only its own 16 rows)
        #pragma unroll
        for (int nj = 0; nj < 4; ++nj)
            #pragma unroll
            for (int r = 0; r < 4; ++r) {
                int qloc = w * 16 + quad * 4 + r;
                Ps[qloc][swz(qloc, nj * 16 + l15)] = f2bf(p[nj][r]);
            }

        // O += P @ V (same-wave LDS RAW; compiler orders via lgkmcnt)
        #pragma unroll
        for (int kk = 0; kk < 2; ++kk) {
            int m = w * 16 + l15;
            bf16x8 pa = *(const bf16x8*)&Ps[m][swz(m, kk * 32 + quad * 8)];
            #pragma unroll
            for (int nj = 0; nj < 4; ++nj) {
                int n = nj * 16 + l15;
                bf16x8 vb = *(const bf16x8*)&VsT[n][swz(n, kk * 32 + quad * 8)];
                o[nj] = __builtin_amdgcn_mfma_f32_16x16x32_bf16(pa, vb, o[nj], 0, 0, 0);
            }
        }
    }

    // epilogue: normalize, write merge-heads bf16 [B*S][1024]
    #pragma unroll
    for (int r = 0; r < 4; ++r) {
        float inv = 1.0f / lrow[r];
        int row = qb * 64 + w * 16 + quad * 4 + r;
        size_t obase = ((size_t)b * SS + row) * 1024 + h * 64;
        #pragma unroll
        for (int nj = 0; nj < 4; ++nj)
            aout[obase + nj * 16 + l15] = f2bf(o[nj][r] * inv);
    }
}

extern "C" void kernel_launch(void* const* d_in, const int* in_sizes, int n_in,
                              void* d_out, int out_size, void* d_ws, size_t ws_size,
                              hipStream_t stream)
{
    const float* x     = (const float*)d_in[0];
    const float* wqkv  = (const float*)d_in[1];
    const float* bqkv  = (const float*)d_in[2];
    const float* wproj = (const float*)d_in[3];
    const float* bproj = (const float*)d_in[4];
    float* out = (float*)d_out;

    // workspace layout (bf16 elements): 28M shorts = 56 MB
    unsigned short* ws   = (unsigned short*)d_ws;
    unsigned short* Xb   = ws;                                  // 4096*1024
    unsigned short* W1t  = Xb  + (size_t)4096 * 1024;           // 3072*1024
    unsigned short* W2t  = W1t + (size_t)3072 * 1024;           // 1024*1024
    unsigned short* qkv  = W2t + (size_t)1024 * 1024;           // 4096*3072
    unsigned short* Vt   = qkv + (size_t)4096 * 3072;           // 64*64*1024
    unsigned short* abuf = Vt  + (size_t)64 * 64 * 1024;        // 4096*1024

    cast_bf16_kernel<<<4096, 256, 0, stream>>>(x, Xb, 4096 * 1024 / 4);
    tcast_kernel<<<dim3(3072 / 64, 1024 / 64), 256, 0, stream>>>(wqkv, W1t, 1024, 3072);
    tcast_kernel<<<dim3(1024 / 64, 1024 / 64), 256, 0, stream>>>(wproj, W2t, 1024, 1024);

    gemm_mfma<true><<<dim3(3072 / 128, 4096 / 128), 256, 0, stream>>>(
        Xb, W1t, bqkv, qkv, 3072, 1024);

    vtrans_kernel<<<dim3(16, 64), 256, 0, stream>>>(qkv, Vt);
    attn_mfma<<<dim3(16, 64), 256, 0, stream>>>(qkv, Vt, abuf);

    gemm_mfma<false><<<dim3(1024 / 128, 4096 / 128), 256, 0, stream>>>(
        abuf, W2t, bproj, out, 1024, 1024);
}

// Round 3
// 207.687 us; speedup vs baseline: 4.6642x; 1.1592x over previous
//
#include <hip/hip_runtime.h>
#include <math.h>

#define BB 4
#define SS 1024
#define DD 1024
#define HH 16
#define DHH 64
#define NROWS (BB * SS)   // 4096

typedef short bf16x8 __attribute__((ext_vector_type(8)));
typedef float f32x4 __attribute__((ext_vector_type(4)));

// fp32 -> bf16 round-to-nearest-even
__device__ __forceinline__ unsigned short f2bf(float f) {
    unsigned u = __float_as_uint(f);
    u += 0x7fffu + ((u >> 16) & 1u);
    return (unsigned short)(u >> 16);
}

// async global->LDS, 16B per lane; LDS dest = wave-uniform base + lane*16
__device__ __forceinline__ void glds16(const void* g, void* l) {
    __builtin_amdgcn_global_load_lds(
        (const __attribute__((address_space(1))) unsigned int*)g,
        (__attribute__((address_space(3))) unsigned int*)l, 16, 0, 0);
}

// 32B-granule XOR swizzle within a 64-col (128B) logical row (rows padded
// to 80 shorts). Breaks strided MFMA fragment-read bank conflicts.
__device__ __forceinline__ int swz(int row, int col) {
    return ((((col >> 4) ^ (row >> 2)) & 3) << 4) | (col & 15);
}

// ---------------------------------------------------------------------------
// fp32 -> bf16 bulk cast (n4 = element count / 4)
// ---------------------------------------------------------------------------
__global__ __launch_bounds__(256) void cast_bf16_kernel(
    const float* __restrict__ in, unsigned short* __restrict__ out, int n4)
{
    int i = blockIdx.x * 256 + threadIdx.x;
    if (i < n4) {
        float4 v = ((const float4*)in)[i];
        ushort4 o = { f2bf(v.x), f2bf(v.y), f2bf(v.z), f2bf(v.w) };
        ((ushort4*)out)[i] = o;
    }
}

// ---------------------------------------------------------------------------
// W[K][N] fp32 -> Wt[N][K] bf16 (tiled transpose, 64x64 per block)
// ---------------------------------------------------------------------------
__global__ __launch_bounds__(256) void tcast_kernel(
    const float* __restrict__ W, unsigned short* __restrict__ Wt, int K, int N)
{
    __shared__ float tile[64][65];
    int n0 = blockIdx.x * 64, k0 = blockIdx.y * 64;
    int c = threadIdx.x & 63, r0 = threadIdx.x >> 6;
    #pragma unroll
    for (int i = 0; i < 16; ++i) {
        int r = r0 + i * 4;
        tile[r][c] = W[(size_t)(k0 + r) * N + n0 + c];
    }
    __syncthreads();
    #pragma unroll
    for (int i = 0; i < 16; ++i) {
        int r = r0 + i * 4;  // n-local
        Wt[(size_t)(n0 + r) * K + k0 + c] = f2bf(tile[c][r]);
    }
}

// ---------------------------------------------------------------------------
// Extract+transpose V third of qkv: Vt[bh][dh=64][S=1024] bf16
// ---------------------------------------------------------------------------
__global__ __launch_bounds__(256) void vtrans_kernel(
    const unsigned short* __restrict__ qkv, unsigned short* __restrict__ Vt)
{
    __shared__ unsigned short tile[64][65];
    int kb = blockIdx.x;           // S tile
    int bh = blockIdx.y;           // b*16+h
    int b = bh >> 4, h = bh & 15;
    int c = threadIdx.x & 63, r0 = threadIdx.x >> 6;
    size_t base = (size_t)b * SS * 3072 + 2048 + h * 64;
    #pragma unroll
    for (int i = 0; i < 16; ++i) {
        int r = r0 + i * 4;  // key row
        tile[r][c] = qkv[base + (size_t)(kb * 64 + r) * 3072 + c];
    }
    __syncthreads();
    #pragma unroll
    for (int i = 0; i < 16; ++i) {
        int d = r0 + i * 4;  // dh row
        Vt[((size_t)bh * 64 + d) * 1024 + kb * 64 + c] = tile[c][d];
    }
}

// ---------------------------------------------------------------------------
// MFMA bf16 GEMM: C = A[M,K] @ Bt^T + bias. 128x128 tile, BK=64, 4 waves,
// 16x16x32 MFMA, global_load_lds staging. bf16 output goes through an LDS
// round trip so global stores are coalesced bf16x8 (vs 64 scalar b16/thread).
// ---------------------------------------------------------------------------
template <bool OUT_BF16>
__global__ __launch_bounds__(256) void gemm_mfma(
    const unsigned short* __restrict__ A,
    const unsigned short* __restrict__ Bt,
    const float* __restrict__ bias,
    void* __restrict__ Cout, int N, int K)
{
    __shared__ unsigned short smem[128 * 128];   // As: [0,8192) Bs: [8192,16384)
    unsigned short* As = smem;                   // [128][64]
    unsigned short* Bs = smem + 128 * 64;        // [128][64]

    const int t = threadIdx.x;
    const int lane = t & 63;
    const int w = t >> 6;                 // wave 0..3
    const int wm = (w >> 1) * 64;
    const int wn = (w & 1) * 64;
    const int l15 = lane & 15, quad = lane >> 4;
    const int bm = blockIdx.y * 128, bn = blockIdx.x * 128;

    const int srow = lane >> 3;           // 0..7 (row in 8-row chunk)
    const int scol = (lane & 7) * 8;      // 0..56 (bf16 col)

    const f32x4 zero4 = {0.f, 0.f, 0.f, 0.f};
    f32x4 acc[4][4];
    #pragma unroll
    for (int i = 0; i < 4; ++i)
        #pragma unroll
        for (int j = 0; j < 4; ++j) acc[i][j] = zero4;

    const unsigned short* Abase = A  + (size_t)(bm + w * 32 + srow) * K + scol;
    const unsigned short* Bbase = Bt + (size_t)(bn + w * 32 + srow) * K + scol;

    for (int k0 = 0; k0 < K; k0 += 64) {
        #pragma unroll
        for (int c = 0; c < 4; ++c) {
            glds16(Abase + (size_t)(c * 8) * K + k0, &As[(w * 32 + c * 8) * 64]);
            glds16(Bbase + (size_t)(c * 8) * K + k0, &Bs[(w * 32 + c * 8) * 64]);
        }
        __syncthreads();
        #pragma unroll
        for (int kk = 0; kk < 2; ++kk) {
            bf16x8 af[4], bfr[4];
            #pragma unroll
            for (int mi = 0; mi < 4; ++mi)
                af[mi] = *(const bf16x8*)&As[(wm + mi * 16 + l15) * 64 + kk * 32 + quad * 8];
            #pragma unroll
            for (int nj = 0; nj < 4; ++nj)
                bfr[nj] = *(const bf16x8*)&Bs[(wn + nj * 16 + l15) * 64 + kk * 32 + quad * 8];
            #pragma unroll
            for (int mi = 0; mi < 4; ++mi)
                #pragma unroll
                for (int nj = 0; nj < 4; ++nj)
                    acc[mi][nj] = __builtin_amdgcn_mfma_f32_16x16x32_bf16(
                        af[mi], bfr[nj], acc[mi][nj], 0, 0, 0);
        }
        __syncthreads();
    }

    // Epilogue. C/D layout: col = lane&15, row = quad*4 + reg (m89-verified).
    float bv[4];
    #pragma unroll
    for (int nj = 0; nj < 4; ++nj) bv[nj] = bias[bn + wn + nj * 16 + l15];

    if (OUT_BF16) {
        // stage C tile (bf16) into LDS, then coalesced 16B stores
        #pragma unroll
        for (int mi = 0; mi < 4; ++mi)
            #pragma unroll
            for (int nj = 0; nj < 4; ++nj)
                #pragma unroll
                for (int r = 0; r < 4; ++r)
                    smem[(wm + mi * 16 + quad * 4 + r) * 128 + wn + nj * 16 + l15] =
                        f2bf(acc[mi][nj][r] + bv[nj]);
        __syncthreads();
        unsigned short* C = (unsigned short*)Cout;
        #pragma unroll
        for (int i = 0; i < 8; ++i) {
            int off = i * 2048 + t * 8;
            int row = off >> 7, col = off & 127;
            *(bf16x8*)&C[(size_t)(bm + row) * N + bn + col] = *(const bf16x8*)&smem[off];
        }
    } else {
        float* C = (float*)Cout;
        #pragma unroll
        for (int mi = 0; mi < 4; ++mi)
            #pragma unroll
            for (int nj = 0; nj < 4; ++nj) {
                int col = bn + wn + nj * 16 + l15;
                int row0 = bm + wm + mi * 16 + quad * 4;
                #pragma unroll
                for (int r = 0; r < 4; ++r)
                    C[(size_t)(row0 + r) * N + col] = acc[mi][nj][r] + bv[nj];
            }
    }
}

// ---------------------------------------------------------------------------
// Flash attention, bf16 MFMA, PAIRED q-tiles for load balance.
// Block = q-tiles {qlo=bx, qhi=15-bx} of one (b,h): every block computes
// exactly 17 tile-steps. 4 waves; each wave owns rows w*16..w*16+15 of BOTH
// q-tiles. K/V staged once per k-tile serves both.
// ---------------------------------------------------------------------------
__device__ __forceinline__ void attn_tile_step(
    bf16x8 q0, bf16x8 q1, float* mrow, float* lrow, f32x4* o,
    const unsigned short (*Ks)[80], const unsigned short (*VsT)[80],
    unsigned short (*Ps)[80], int w, int l15, int quad, bool diag)
{
    const f32x4 zero4 = {0.f, 0.f, 0.f, 0.f};
    // S = Q K^T
    f32x4 s[4];
    #pragma unroll
    for (int nj = 0; nj < 4; ++nj) {
        int n = nj * 16 + l15;
        f32x4 sa = zero4;
        bf16x8 b0 = *(const bf16x8*)&Ks[n][swz(n, quad * 8)];
        bf16x8 b1 = *(const bf16x8*)&Ks[n][swz(n, 32 + quad * 8)];
        sa = __builtin_amdgcn_mfma_f32_16x16x32_bf16(q0, b0, sa, 0, 0, 0);
        sa = __builtin_amdgcn_mfma_f32_16x16x32_bf16(q1, b1, sa, 0, 0, 0);
        s[nj] = sa;
    }
    const float scale = 0.125f;  // 1/sqrt(64)
    #pragma unroll
    for (int nj = 0; nj < 4; ++nj)
        #pragma unroll
        for (int r = 0; r < 4; ++r) {
            float sv = s[nj][r] * scale;
            if (diag && (nj * 16 + l15) > (w * 16 + quad * 4 + r)) sv = -INFINITY;
            s[nj][r] = sv;
        }

    // online softmax; a q-row lives across lane bits 0..3 (l15)
    float rmax[4];
    #pragma unroll
    for (int r = 0; r < 4; ++r)
        rmax[r] = fmaxf(fmaxf(s[0][r], s[1][r]), fmaxf(s[2][r], s[3][r]));
    #pragma unroll
    for (int off = 1; off < 16; off <<= 1)
        #pragma unroll
        for (int r = 0; r < 4; ++r)
            rmax[r] = fmaxf(rmax[r], __shfl_xor(rmax[r], off));

    float p[4][4], rs[4];
    #pragma unroll
    for (int r = 0; r < 4; ++r) {
        float mn = fmaxf(mrow[r], rmax[r]);
        float al = __expf(mrow[r] - mn);  // exp(-inf)=0 on first tile
        mrow[r] = mn;
        rs[r] = 0.f;
        #pragma unroll
        for (int nj = 0; nj < 4; ++nj) {
            p[nj][r] = __expf(s[nj][r] - mn);
            rs[r] += p[nj][r];
        }
        lrow[r] *= al;
        #pragma unroll
        for (int nj = 0; nj < 4; ++nj) o[nj][r] *= al;
    }
    #pragma unroll
    for (int off = 1; off < 16; off <<= 1)
        #pragma unroll
        for (int r = 0; r < 4; ++r)
            rs[r] += __shfl_xor(rs[r], off);
    #pragma unroll
    for (int r = 0; r < 4; ++r) lrow[r] += rs[r];

    // P: C-layout -> LDS (wave-local rows; same-wave RAW/WAR via lgkmcnt)
    #pragma unroll
    for (int nj = 0; nj < 4; ++nj)
        #pragma unroll
        for (int r = 0; r < 4; ++r) {
            int qloc = w * 16 + quad * 4 + r;
            Ps[qloc][swz(qloc, nj * 16 + l15)] = f2bf(p[nj][r]);
        }

    // O += P @ V
    #pragma unroll
    for (int kk = 0; kk < 2; ++kk) {
        int m = w * 16 + l15;
        bf16x8 pa = *(const bf16x8*)&Ps[m][swz(m, kk * 32 + quad * 8)];
        #pragma unroll
        for (int nj = 0; nj < 4; ++nj) {
            int n = nj * 16 + l15;
            bf16x8 vb = *(const bf16x8*)&VsT[n][swz(n, kk * 32 + quad * 8)];
            o[nj] = __builtin_amdgcn_mfma_f32_16x16x32_bf16(pa, vb, o[nj], 0, 0, 0);
        }
    }
}

__global__ __launch_bounds__(256) void attn_mfma(
    const unsigned short* __restrict__ qkv,  // [B*S][3072] bf16
    const unsigned short* __restrict__ Vt,   // [bh][64][1024] bf16
    unsigned short* __restrict__ aout)       // [B*S][1024] bf16
{
    __shared__ unsigned short Ks[64][80];
    __shared__ unsigned short VsT[64][80];
    __shared__ unsigned short Ps[64][80];

    const int t = threadIdx.x;
    const int lane = t & 63;
    const int w = t >> 6;
    const int l15 = lane & 15, quad = lane >> 4;
    const int qlo = blockIdx.x;        // 0..7
    const int qhi = 15 - qlo;          // 15..8
    const int bh = blockIdx.y;
    const int b = bh >> 4, h = bh & 15;
    const size_t qkvbase = (size_t)b * SS * 3072;
    const f32x4 zero4 = {0.f, 0.f, 0.f, 0.f};

    // stage Q tiles through Ks, read fragments
    bf16x8 qfl[2], qfh[2];
    {
        int g = t;
        #pragma unroll
        for (int it = 0; it < 2; ++it, g += 256) {
            int r = g >> 3, cc = (g & 7) * 8;
            bf16x8 v = *(const bf16x8*)&qkv[qkvbase + (size_t)(qlo * 64 + r) * 3072 + h * 64 + cc];
            *(bf16x8*)&Ks[r][swz(r, cc)] = v;
        }
    }
    __syncthreads();
    {
        int m = w * 16 + l15;
        qfl[0] = *(const bf16x8*)&Ks[m][swz(m, quad * 8)];
        qfl[1] = *(const bf16x8*)&Ks[m][swz(m, 32 + quad * 8)];
    }
    __syncthreads();
    {
        int g = t;
        #pragma unroll
        for (int it = 0; it < 2; ++it, g += 256) {
            int r = g >> 3, cc = (g & 7) * 8;
            bf16x8 v = *(const bf16x8*)&qkv[qkvbase + (size_t)(qhi * 64 + r) * 3072 + h * 64 + cc];
            *(bf16x8*)&Ks[r][swz(r, cc)] = v;
        }
    }
    __syncthreads();
    {
        int m = w * 16 + l15;
        qfh[0] = *(const bf16x8*)&Ks[m][swz(m, quad * 8)];
        qfh[1] = *(const bf16x8*)&Ks[m][swz(m, 32 + quad * 8)];
    }

    float mL[4], lL[4], mH[4], lH[4];
    f32x4 oL[4], oH[4];
    #pragma unroll
    for (int r = 0; r < 4; ++r) { mL[r] = -INFINITY; lL[r] = 0.f; mH[r] = -INFINITY; lH[r] = 0.f; }
    #pragma unroll
    for (int nj = 0; nj < 4; ++nj) { oL[nj] = zero4; oH[nj] = zero4; }

    for (int kb = 0; kb <= qhi; ++kb) {
        __syncthreads();  // previous tile reads done (and qfh reads on iter 0)
        {
            int g = t;
            #pragma unroll
            for (int it = 0; it < 2; ++it, g += 256) {
                int r = g >> 3, cc = (g & 7) * 8;
                bf16x8 kv = *(const bf16x8*)&qkv[qkvbase + (size_t)(kb * 64 + r) * 3072 + 1024 + h * 64 + cc];
                *(bf16x8*)&Ks[r][swz(r, cc)] = kv;
                bf16x8 vv = *(const bf16x8*)&Vt[((size_t)bh * 64 + r) * 1024 + kb * 64 + cc];
                *(bf16x8*)&VsT[r][swz(r, cc)] = vv;
            }
        }
        __syncthreads();

        if (kb <= qlo)
            attn_tile_step(qfl[0], qfl[1], mL, lL, oL, Ks, VsT, Ps,
                           w, l15, quad, kb == qlo);
        attn_tile_step(qfh[0], qfh[1], mH, lH, oH, Ks, VsT, Ps,
                       w, l15, quad, kb == qhi);
    }

    // epilogue: normalize, write merge-heads bf16 [B*S][1024]
    #pragma unroll
    for (int r = 0; r < 4; ++r) {
        float invL = 1.0f / lL[r];
        float invH = 1.0f / lH[r];
        int rloc = w * 16 + quad * 4 + r;
        size_t obL = ((size_t)b * SS + qlo * 64 + rloc) * 1024 + h * 64;
        size_t obH = ((size_t)b * SS + qhi * 64 + rloc) * 1024 + h * 64;
        #pragma unroll
        for (int nj = 0; nj < 4; ++nj) {
            aout[obL + nj * 16 + l15] = f2bf(oL[nj][r] * invL);
            aout[obH + nj * 16 + l15] = f2bf(oH[nj][r] * invH);
        }
    }
}

extern "C" void kernel_launch(void* const* d_in, const int* in_sizes, int n_in,
                              void* d_out, int out_size, void* d_ws, size_t ws_size,
                              hipStream_t stream)
{
    const float* x     = (const float*)d_in[0];
    const float* wqkv  = (const float*)d_in[1];
    const float* bqkv  = (const float*)d_in[2];
    const float* wproj = (const float*)d_in[3];
    const float* bproj = (const float*)d_in[4];
    float* out = (float*)d_out;

    unsigned short* ws   = (unsigned short*)d_ws;
    unsigned short* Xb   = ws;                                  // 4096*1024
    unsigned short* W1t  = Xb  + (size_t)4096 * 1024;           // 3072*1024
    unsigned short* W2t  = W1t + (size_t)3072 * 1024;           // 1024*1024
    unsigned short* qkv  = W2t + (size_t)1024 * 1024;           // 4096*3072
    unsigned short* Vt   = qkv + (size_t)4096 * 3072;           // 64*64*1024
    unsigned short* abuf = Vt  + (size_t)64 * 64 * 1024;        // 4096*1024

    cast_bf16_kernel<<<4096, 256, 0, stream>>>(x, Xb, 4096 * 1024 / 4);
    tcast_kernel<<<dim3(3072 / 64, 1024 / 64), 256, 0, stream>>>(wqkv, W1t, 1024, 3072);
    tcast_kernel<<<dim3(1024 / 64, 1024 / 64), 256, 0, stream>>>(wproj, W2t, 1024, 1024);

    gemm_mfma<true><<<dim3(3072 / 128, 4096 / 128), 256, 0, stream>>>(
        Xb, W1t, bqkv, qkv, 3072, 1024);

    vtrans_kernel<<<dim3(16, 64), 256, 0, stream>>>(qkv, Vt);
    attn_mfma<<<dim3(8, 64), 256, 0, stream>>>(qkv, Vt, abuf);

    gemm_mfma<false><<<dim3(1024 / 128, 4096 / 128), 256, 0, stream>>>(
        abuf, W2t, bproj, out, 1024, 1024);
}